// Round 17
// baseline (134.995 us; speedup 1.0000x reference)
//
#include <hip/hip_runtime.h>
#include <hip/hip_bf16.h>

typedef _Float16 half8 __attribute__((ext_vector_type(8)));
typedef _Float16 half4v __attribute__((ext_vector_type(4)));
typedef __fp16 fp16x2 __attribute__((ext_vector_type(2)));   // cvt_pkrtz return type
typedef float floatx4 __attribute__((ext_vector_type(4)));
typedef float floatx16 __attribute__((ext_vector_type(16)));

// Problem constants: B=8, N=1024, D=512, H=8, DH=64
#define BB 8
#define NN 1024
#define DD 512
#define HH 8
#define DHH 64
#define LOG2E 1.4426950408889634f

// hardware 2^x (v_exp_f32)
#define EXP2F(x) __builtin_amdgcn_exp2f(x)

// async global->LDS, 16B per lane, dest = wave-uniform base + lane*16
__device__ __forceinline__ void gload_lds16(const _Float16* g, _Float16* l) {
    __builtin_amdgcn_global_load_lds(
        (const __attribute__((address_space(1))) void*)g,
        (__attribute__((address_space(3))) void*)l, 16, 0, 0);
}

// ---------------- W fp32->fp16 transpose only (round-8 version) ----------------
__global__ __launch_bounds__(256) void cvt_kernel(const float* __restrict__ Wq,
                                                  const float* __restrict__ Wk,
                                                  const float* __restrict__ Wv,
                                                  _Float16* __restrict__ Wt) {
    __shared__ __align__(16) _Float16 tb[64][72];
    int t = blockIdx.x;                // 0..191
    int tid = threadIdx.x;
    int which = t >> 6;                // /64
    int rem = t & 63;
    int kt = (rem >> 3) * 64, nt = (rem & 7) * 64;
    const float* W = (which == 0) ? Wq : (which == 1) ? Wk : Wv;
    float wscale = (which == 0) ? LOG2E : 1.0f;
    _Float16* Wto = Wt + (size_t)which * DD * DD;
    for (int i = 0; i < 16; i++) {
        int idx = tid + i * 256;
        int r = idx >> 6, c = idx & 63;
        tb[c][r] = (_Float16)(W[(size_t)(kt + r) * DD + nt + c] * wscale);
    }
    __syncthreads();
    for (int i = 0; i < 16; i++) {
        int idx = tid + i * 256;
        int r = idx >> 6, c = idx & 63;
        Wto[(size_t)(nt + r) * DD + kt + c] = tb[r][c];
    }
}

// ---------------- QKV projection, 128x128 tile (round-8/12 version, BK=32) ----------------
__global__ __launch_bounds__(256) void qkv_gemm_kernel(const float* __restrict__ x,
                                                       const _Float16* __restrict__ Wt,
                                                       const float* __restrict__ bq,
                                                       const float* __restrict__ bk,
                                                       const float* __restrict__ bv,
                                                       _Float16* __restrict__ QKV) {
    __shared__ __align__(16) _Float16 Ws[128 * 32];   // W rows (features)
    __shared__ __align__(16) _Float16 Xs[128 * 32];   // x rows (tokens)

    int which = blockIdx.z;
    const _Float16* Wtw = Wt + (size_t)which * DD * DD;
    const float* bias = (which == 0) ? bq : (which == 1) ? bk : bv;
    const float bscale = (which == 0) ? LOG2E : 1.0f;

    int tid = threadIdx.x;
    int wave = tid >> 6, lane = tid & 63;
    int quad = lane >> 4, l16 = lane & 15;
    int wm = wave >> 1, wn = wave & 1;
    int mBase = blockIdx.x * 128;   // tokens  (token-major for XCD L2 reuse)
    int nBase = blockIdx.y * 128;   // features

    int srow = wave * 32 + (lane >> 2);
    int scol = (lane & 3) * 8;
    const _Float16* wg = Wtw + (size_t)(nBase + srow) * DD + scol;
    const float*    xg = x   + (size_t)(mBase + srow) * DD + scol;
    _Float16* wl = Ws + (wave * 32) * 32;

    floatx4 acc[4][4];
    for (int i = 0; i < 4; i++)
        for (int j = 0; j < 4; j++) acc[i][j] = (floatx4){0.f, 0.f, 0.f, 0.f};

    for (int kk = 0; kk < DD; kk += 32) {
        __syncthreads();
        gload_lds16(wg + kk,           wl);
        gload_lds16(wg + 16 * DD + kk, wl + 16 * 32);
        float4 a0 = *(const float4*)(xg + kk);
        float4 a1 = *(const float4*)(xg + kk + 4);
        float4 b0 = *(const float4*)(xg + 16 * DD + kk);
        float4 b1 = *(const float4*)(xg + 16 * DD + kk + 4);
        half8 ha, hb;
        ha[0] = (_Float16)a0.x; ha[1] = (_Float16)a0.y; ha[2] = (_Float16)a0.z; ha[3] = (_Float16)a0.w;
        ha[4] = (_Float16)a1.x; ha[5] = (_Float16)a1.y; ha[6] = (_Float16)a1.z; ha[7] = (_Float16)a1.w;
        hb[0] = (_Float16)b0.x; hb[1] = (_Float16)b0.y; hb[2] = (_Float16)b0.z; hb[3] = (_Float16)b0.w;
        hb[4] = (_Float16)b1.x; hb[5] = (_Float16)b1.y; hb[6] = (_Float16)b1.z; hb[7] = (_Float16)b1.w;
        *(half8*)&Xs[srow * 32 + scol] = ha;
        *(half8*)&Xs[(srow + 16) * 32 + scol] = hb;
        __syncthreads();

        half8 af[4], bf[4];
        if (which < 2) {
            for (int i = 0; i < 4; i++)
                af[i] = *(const half8*)&Ws[(wm * 64 + i * 16 + l16) * 32 + quad * 8];
            for (int j = 0; j < 4; j++)
                bf[j] = *(const half8*)&Xs[(wn * 64 + j * 16 + l16) * 32 + quad * 8];
        } else {
            for (int i = 0; i < 4; i++)
                af[i] = *(const half8*)&Xs[(wm * 64 + i * 16 + l16) * 32 + quad * 8];
            for (int j = 0; j < 4; j++)
                bf[j] = *(const half8*)&Ws[(wn * 64 + j * 16 + l16) * 32 + quad * 8];
        }
        for (int i = 0; i < 4; i++)
            for (int j = 0; j < 4; j++)
                acc[i][j] = __builtin_amdgcn_mfma_f32_16x16x32_f16(af[i], bf[j], acc[i][j], 0, 0, 0);
    }

    if (which < 2) {
        _Float16* out = QKV + (size_t)which * (BB * NN) * DD;
        for (int i = 0; i < 4; i++) {
            int feat0 = nBase + wm * 64 + i * 16 + quad * 4;
            float4 b4 = *(const float4*)&bias[feat0];
            b4.x *= bscale; b4.y *= bscale; b4.z *= bscale; b4.w *= bscale;
            for (int j = 0; j < 4; j++) {
                int token = mBase + wn * 64 + j * 16 + l16;
                half4v pack;
                pack[0] = (_Float16)(acc[i][j][0] + b4.x);
                pack[1] = (_Float16)(acc[i][j][1] + b4.y);
                pack[2] = (_Float16)(acc[i][j][2] + b4.z);
                pack[3] = (_Float16)(acc[i][j][3] + b4.w);
                *(half4v*)&out[(size_t)token * DD + feat0] = pack;
            }
        }
    } else {
        _Float16* VT = QKV + (size_t)2 * (BB * NN) * DD;
        for (int j = 0; j < 4; j++) {
            int col = nBase + wn * 64 + j * 16 + l16;
            float bval = bias[col];
            for (int i = 0; i < 4; i++) {
                int row0 = mBase + wm * 64 + i * 16 + quad * 4;
                int b = row0 >> 10;
                int n = row0 & 1023;
                half4v pack;
                for (int reg = 0; reg < 4; reg++) pack[reg] = (_Float16)(acc[i][j][reg] + bval);
                *(half4v*)&VT[((size_t)b * 512 + col) * 1024 + n] = pack;
            }
        }
    }
}

// ---------------- flash attention, 32x32 MFMA, SPLIT-K (2 key-halves / block) ----------------
// Round 17: the serial tile-chain (16 dependent K-tiles per wave) is the one
// quantity no prior experiment varied — issue cuts (r14), drain/locality/softmax
// fixes (r4/5/7) were all null while time tracked chain length. Split-K halves
// it: 4 waves/block = (khalf, qsub); wave computes 32 q-rows over 8 tiles
// (keys khalf*512..+511) with the verified round-14 core; two single-buffered
// K/V pipelines (exposed staging measured-null in r0/r4); end flash-merge of
// the two partials (o,m,l) via LDS scratch (K/V dead), waves 0/1 store.
// Waves/CU: 8 -> 16. LDS 32KB -> 4 blocks/CU. grid 1024, block 256.
__global__ __launch_bounds__(256) void attn_kernel(const _Float16* __restrict__ QKV,
                                                   float* __restrict__ out) {
    const _Float16* Q  = QKV;
    const _Float16* K  = QKV + (size_t)(BB * NN) * DD;
    const _Float16* VT = QKV + (size_t)2 * (BB * NN) * DD;

    __shared__ __align__(16) _Float16 Kt[2][64 * 64];   // per-khalf [key][d], swizzled
    __shared__ __align__(16) _Float16 Vt[2][64 * 64];   // per-khalf [d][key], swizzled

    int tid = threadIdx.x;
    int wave = tid >> 6, lane = tid & 63;
    int qsub = wave & 1, khalf = wave >> 1;
    int l31 = lane & 31, hf = lane >> 5;
    int xr = l31 & 7;
    // XCD-pinned decode: bid&7 = batch b per XCD.
    int bid = blockIdx.x;
    int b = bid & 7;
    int local = bid >> 3;      // 0..127
    int h = local & 7;
    int qt = local >> 3;       // 0..15

    const _Float16* Qb  = Q + ((size_t)b * NN) * DD + h * DHH;
    const _Float16* Kb  = K + ((size_t)b * NN) * DD + h * DHH;
    const _Float16* VTb = VT + ((size_t)b * 512 + h * 64) * 1024;

    // Q B-frags: col=lane&31=q, k=(lane>>5)*8+reg over d; 4 slices of 16 d.
    int qrow = qt * 64 + qsub * 32 + l31;
    half8 qf[4];
    for (int sl = 0; sl < 4; sl++)
        qf[sl] = *(const half8*)(Qb + (size_t)qrow * DD + sl * 16 + hf * 8);

    floatx16 o0, o1;
    for (int i = 0; i < 16; i++) { o0[i] = 0.f; o1[i] = 0.f; }
    float m_i = 0.0f, l_i = 0.f;   // exp-first: m init 0

    // staging (pre-swizzled global src, linear LDS dest); within a pipeline the
    // two waves (qsub 0/1) each stage 32 K-rows and 32 V-d-rows.
    int srow = lane >> 3;
    int schunk = (lane & 7) ^ srow;
    const _Float16* kg = Kb + (size_t)(qsub * 32 + srow) * DD + schunk * 8;
    const _Float16* vg = VTb + (size_t)(qsub * 32 + srow) * 1024 + schunk * 8;
    _Float16* kl = &Kt[khalf][(qsub * 32) * 64];
    _Float16* vl = &Vt[khalf][(qsub * 32) * 64];

    const _Float16* Kc = &Kt[khalf][0];
    const _Float16* Vc = &Vt[khalf][0];

    for (int t = 0; t < 8; t++) {
        int gt = khalf * 8 + t;            // global tile index (keys gt*64..+63)
        __syncthreads();                   // buffer free (all waves done with prev tile)
        for (int j = 0; j < 4; j++) {
            gload_lds16(kg + (size_t)(gt * 64 + j * 8) * DD, kl + (j * 8) * 64);
            gload_lds16(vg + (size_t)(j * 8) * 1024 + gt * 64, vl + (j * 8) * 64);
        }
        __syncthreads();                   // staged (implicit full drain)

        // ---- QK^T: S^T[key][q], two 32-key subtiles, K=16 slices over d ----
        floatx16 s0, s1;
        for (int i = 0; i < 16; i++) { s0[i] = 0.f; s1[i] = 0.f; }
        __builtin_amdgcn_s_setprio(1);
        for (int sl = 0; sl < 4; sl++) {
            int c = sl * 2 + hf;
            half8 kf0 = *(const half8*)&Kc[l31 * 64 + ((c ^ xr) * 8)];
            half8 kf1 = *(const half8*)&Kc[(32 + l31) * 64 + ((c ^ xr) * 8)];
            s0 = __builtin_amdgcn_mfma_f32_32x32x16_f16(kf0, qf[sl], s0, 0, 0, 0);
            s1 = __builtin_amdgcn_mfma_f32_32x32x16_f16(kf1, qf[sl], s1, 0, 0, 0);
        }
        __builtin_amdgcn_s_setprio(0);

        // ---- exp-first softmax (stale m), max off critical path ----
        float mx = s0[0];
        for (int i = 1; i < 16; i++) mx = fmaxf(mx, s0[i]);
        for (int i = 0; i < 16; i++) mx = fmaxf(mx, s1[i]);

        for (int i = 0; i < 16; i++) s0[i] = EXP2F(s0[i] - m_i);
        for (int i = 0; i < 16; i++) s1[i] = EXP2F(s1[i] - m_i);
        float rs = 0.f;
        for (int i = 0; i < 16; i++) rs += s0[i];
        for (int i = 0; i < 16; i++) rs += s1[i];

        mx = fmaxf(mx, __shfl_xor(mx, 32, 64));
        rs += __shfl_xor(rs, 32, 64);

        if (__any(mx > m_i + 11.5443f)) {
            float mnew = fmaxf(m_i, mx);
            float al = EXP2F(m_i - mnew);
            m_i = mnew;
            l_i *= al;
            rs *= al;
            for (int i = 0; i < 16; i++) {
                s0[i] *= al; s1[i] *= al;
                o0[i] *= al; o1[i] *= al;
            }
        }
        l_i += rs;

        // ---- PV: o^T[d][q] += V^T[d][k] x P[k][q], P direct from C-layout ----
        __builtin_amdgcn_s_setprio(1);
        for (int sub = 0; sub < 2; sub++) {
            const floatx16& S = sub ? s1 : s0;
            for (int h16 = 0; h16 < 2; h16++) {
                fp16x2 p0 = __builtin_amdgcn_cvt_pkrtz(S[h16 * 8 + 0], S[h16 * 8 + 1]);
                fp16x2 p1 = __builtin_amdgcn_cvt_pkrtz(S[h16 * 8 + 2], S[h16 * 8 + 3]);
                fp16x2 p2 = __builtin_amdgcn_cvt_pkrtz(S[h16 * 8 + 4], S[h16 * 8 + 5]);
                fp16x2 p3 = __builtin_amdgcn_cvt_pkrtz(S[h16 * 8 + 6], S[h16 * 8 + 7]);
                half8 pf;
                pf[0] = (_Float16)p0[0]; pf[1] = (_Float16)p0[1];
                pf[2] = (_Float16)p1[0]; pf[3] = (_Float16)p1[1];
                pf[4] = (_Float16)p2[0]; pf[5] = (_Float16)p2[1];
                pf[6] = (_Float16)p3[0]; pf[7] = (_Float16)p3[1];
                int c1 = sub * 4 + h16 * 2;
                {
                    const _Float16* base = &Vc[l31 * 64];
                    half4v v0 = *(const half4v*)(base + ((c1 ^ xr) * 8) + 4 * hf);
                    half4v v1 = *(const half4v*)(base + (((c1 + 1) ^ xr) * 8) + 4 * hf);
                    half8 vf;
                    vf[0] = v0[0]; vf[1] = v0[1]; vf[2] = v0[2]; vf[3] = v0[3];
                    vf[4] = v1[0]; vf[5] = v1[1]; vf[6] = v1[2]; vf[7] = v1[3];
                    o0 = __builtin_amdgcn_mfma_f32_32x32x16_f16(vf, pf, o0, 0, 0, 0);
                }
                {
                    const _Float16* base = &Vc[(32 + l31) * 64];
                    half4v v0 = *(const half4v*)(base + ((c1 ^ xr) * 8) + 4 * hf);
                    half4v v1 = *(const half4v*)(base + (((c1 + 1) ^ xr) * 8) + 4 * hf);
                    half8 vf;
                    vf[0] = v0[0]; vf[1] = v0[1]; vf[2] = v0[2]; vf[3] = v0[3];
                    vf[4] = v1[0]; vf[5] = v1[1]; vf[6] = v1[2]; vf[7] = v1[3];
                    o1 = __builtin_amdgcn_mfma_f32_32x32x16_f16(vf, pf, o1, 0, 0, 0);
                }
            }
        }
        __builtin_amdgcn_s_setprio(0);
    }

    // ---- split-K merge: khalf=1 partials -> LDS scratch (K/V dead); waves 0/1 merge+store ----
    float* scA = (float*)&Kt[0][0];   // 16KB: o0 partials, [pw][lane][16]
    float* scB = (float*)&Vt[0][0];   // 16KB: o1 + m + l,  [pw][lane][18]
    __syncthreads();
    if (wave >= 2) {
        int bA = ((wave - 2) * 64 + lane) * 16;
        int bB = ((wave - 2) * 64 + lane) * 18;
        for (int i = 0; i < 16; i++) scA[bA + i] = o0[i];
        for (int i = 0; i < 16; i++) scB[bB + i] = o1[i];
        scB[bB + 16] = m_i;
        scB[bB + 17] = l_i;
    }
    __syncthreads();
    if (wave < 2) {
        int bA = (wave * 64 + lane) * 16;
        int bB = (wave * 64 + lane) * 18;
        float pm = scB[bB + 16], pl = scB[bB + 17];
        float M = fmaxf(m_i, pm);
        float a = EXP2F(m_i - M);
        float bw = EXP2F(pm - M);
        float lm = l_i * a + pl * bw;
        float inv = 1.0f / lm;
        float* outb = out + ((size_t)b * NN) * DD + h * DHH;
        for (int g = 0; g < 4; g++) {
            float4 st;
            st.x = (o0[g * 4 + 0] * a + scA[bA + g * 4 + 0] * bw) * inv;
            st.y = (o0[g * 4 + 1] * a + scA[bA + g * 4 + 1] * bw) * inv;
            st.z = (o0[g * 4 + 2] * a + scA[bA + g * 4 + 2] * bw) * inv;
            st.w = (o0[g * 4 + 3] * a + scA[bA + g * 4 + 3] * bw) * inv;
            *(float4*)&outb[(size_t)qrow * DD + g * 8 + 4 * hf] = st;
        }
        for (int g = 0; g < 4; g++) {
            float4 st;
            st.x = (o1[g * 4 + 0] * a + scB[bB + g * 4 + 0] * bw) * inv;
            st.y = (o1[g * 4 + 1] * a + scB[bB + g * 4 + 1] * bw) * inv;
            st.z = (o1[g * 4 + 2] * a + scB[bB + g * 4 + 2] * bw) * inv;
            st.w = (o1[g * 4 + 3] * a + scB[bB + g * 4 + 3] * bw) * inv;
            *(float4*)&outb[(size_t)qrow * DD + 32 + g * 8 + 4 * hf] = st;
        }
    }
}

extern "C" void kernel_launch(void* const* d_in, const int* in_sizes, int n_in,
                              void* d_out, int out_size, void* d_ws, size_t ws_size,
                              hipStream_t stream) {
    const float* x  = (const float*)d_in[0];
    const float* Wq = (const float*)d_in[1];
    const float* bq = (const float*)d_in[2];
    const float* Wk = (const float*)d_in[3];
    const float* bk = (const float*)d_in[4];
    const float* Wv = (const float*)d_in[5];
    const float* bv = (const float*)d_in[6];
    float* out = (float*)d_out;

    _Float16* Wt  = (_Float16*)d_ws;
    _Float16* QKV = Wt + (size_t)3 * DD * DD;

    hipLaunchKernelGGL(cvt_kernel, dim3(192), dim3(256), 0, stream,
                       Wq, Wk, Wv, Wt);
    hipLaunchKernelGGL(qkv_gemm_kernel, dim3(64, 4, 3), dim3(256), 0, stream,
                       x, Wt, bq, bk, bv, QKV);
    hipLaunchKernelGGL(attn_kernel, dim3(1024), dim3(256), 0, stream, QKV, out);
}